// Round 5
// baseline (2741.764 us; speedup 1.0000x reference)
//
#include <hip/hip_runtime.h>

// FPS: input [8, 65536, 3] f32 -> (idx [8,1024] as f32 values, sampled [8,1024,3] f32)
// concatenated flat in d_out.
//
// R19 = R14 proven protocol, fan-in narrowed: WPB 32->8, PPT 4->16.
//
// Rationale (R14 counter decomposition): per-iter ~4900cy = ~230cy dist+reduce
// + ~2000-2300cy fixed IF round trip (sc0 loads always miss XCD L2: 135KB/iter
// FETCH) + ~2300cy fan-in straggle (detection waits for the SLOWEST of 32
// publishers; 32 pollers x 32 records amplify contention — R15/R16 showed the
// straggle term grows super-linearly with width). We cannot shorten the IF
// latency (R17: plain-store tier marginal; R18: atomic-read path killed the
// container — abandoned). So pay it narrower: 8 publishers/8 records per
// batch. VALU grows 4x (~500cy wall, still << exchange), straggle collapses
// toward the fixed term.
//
// Protocol is R14 verbatim otherwise: single poller wave0 (8 poll lanes),
// publisher wave1 (sc0/L2 publish + agent-scope IF mirror), pipelined 2-deep
// poll with 128-round timeout -> sticky IF fallback, __syncthreads barrier2,
// LDS bc4/bn2 broadcast, deferred output store, 128B AoS records (one line
// per record — R15/R16 proved shared-line layouts regress).
//
// Ties resolve to the smallest global index (numpy argmax first-occurrence);
// distances are uncontracted fp32 in reference order -> bit-exact.
// Records: 3x 8B self-tagged words (round tag in low16 of each), parity
// double-buffered; stale/poisoned words never match a future tag; per-word
// tags make mixed-age words harmless. Slot reuse at t+2 ordered by tag
// transitivity through barrier2 + barrier1's full drain. IF fallback
// (wave-uniform) keeps correctness independent of block->XCD placement.

#define NB    8
#define NPTS  65536
#define NSAMP 1024
#define WPB   8      // workgroups per batch (was 32)
#define TPB   512    // threads per workgroup (8 waves)
#define NWAVE 8
#define PPT   16     // points per thread (WPB*TPB*PPT == NPTS)
#define RECQ  16     // 16 ull = 128 B per record line

typedef unsigned long long ull;

#define DPP(x, ctrl) \
  ((unsigned)__builtin_amdgcn_update_dpp((int)(x), (int)(x), (ctrl), 0xf, 0xf, false))

// max over 64 lanes -> uniform; row_shr:N = 0x110|N, bcast15=0x142, bcast31=0x143
__device__ __forceinline__ unsigned umax_wave64(unsigned x) {
  unsigned t;
  t = DPP(x, 0x111); x = t > x ? t : x;
  t = DPP(x, 0x112); x = t > x ? t : x;
  t = DPP(x, 0x114); x = t > x ? t : x;
  t = DPP(x, 0x118); x = t > x ? t : x;
  t = DPP(x, 0x142); x = t > x ? t : x;   // bcast15: row r lane15 -> row r+1
  t = DPP(x, 0x143); x = t > x ? t : x;   // bcast31: lane31 -> rows 2,3
  return (unsigned)__builtin_amdgcn_readlane((int)x, 63);
}
// max over lanes 0..7 -> uniform via lane7 (groups of 16 see their row's shr)
__device__ __forceinline__ unsigned umax_low8(unsigned x) {
  unsigned t;
  t = DPP(x, 0x111); x = t > x ? t : x;
  t = DPP(x, 0x112); x = t > x ? t : x;
  t = DPP(x, 0x114); x = t > x ? t : x;
  return (unsigned)__builtin_amdgcn_readlane((int)x, 7);
}

// 3x 8B loads, NO waitcnt (pipelined polling: caller manages vmcnt).
__device__ __forceinline__ void ld3_issue(const ull* p, ull& a, ull& b, ull& c) {
  asm volatile(
      "global_load_dwordx2 %0, %3, off sc0\n\t"
      "global_load_dwordx2 %1, %3, off offset:8 sc0\n\t"
      "global_load_dwordx2 %2, %3, off offset:16 sc0"
      : "=&v"(a), "=&v"(b), "=&v"(c) : "v"(p) : "memory");
}
// wait until <=3 loads outstanding; data threaded via "+v" for SSA ordering.
__device__ __forceinline__ void wait3_touch(ull& a, ull& b, ull& c) {
  asm volatile("s_waitcnt vmcnt(3)" : "+v"(a), "+v"(b), "+v"(c) :: "memory");
}
__device__ __forceinline__ void wait_vm0() {
  asm volatile("s_waitcnt vmcnt(0)" ::: "memory");
}
// 3x 8B stores, fire-and-forget (write-through to coherence point).
__device__ __forceinline__ void st3_sc0(ull* p, ull a, ull b, ull c) {
  asm volatile(
      "global_store_dwordx2 %3, %0, off sc0\n\t"
      "global_store_dwordx2 %3, %1, off offset:8 sc0\n\t"
      "global_store_dwordx2 %3, %2, off offset:16 sc0"
      :: "v"(a), "v"(b), "v"(c), "v"(p) : "memory");
}

// stage2: select WG winner from red[8][5]; packed words + winning lane
__device__ __forceinline__ void stage2_pack(const unsigned (*red)[5], int lane,
                                            ull tag, ull& w0, ull& w1, ull& w2,
                                            int& ewin) {
  const int e = lane & 7;
  const unsigned d2 = red[e][0];
  const unsigned nn = red[e][1];
  const unsigned mx = umax_low8(d2);
  const ull bb = __ballot(d2 == mx) & 0xFFull;
  if (__popcll(bb) == 1) {
    ewin = __ffsll(bb) - 1;
  } else {
    const unsigned v = (d2 == mx) ? (65535u - nn) : 0u;   // max -> smallest n
    const unsigned mv = umax_low8(v);
    const ull b2 = __ballot((d2 == mx) && (v == mv)) & 0xFFull;
    ewin = __ffsll(b2) - 1;
  }
  const ull k2 = ((ull)d2 << 16) | (ull)(65535u - nn);
  const unsigned xb = red[e][2], yb = red[e][3], zb = red[e][4];
  w0 = (k2 << 16) | tag;
  w1 = ((ull)xb << 32) | ((ull)(yb >> 16) << 16) | tag;
  w2 = ((ull)(yb & 0xFFFFu) << 48) | ((ull)zb << 16) | tag;
}

__global__ __launch_bounds__(TPB, 2)
void fps_kernel(const float* __restrict__ pts, float* __restrict__ out,
                ull* __restrict__ ws) {
  const int wg   = blockIdx.x;   // 0..63
  const int b    = wg >> 3;      // batch: contiguous blocks 8b..8b+7
  const int w    = wg & 7;       // wg within batch, 0..7
  const int tid  = threadIdx.x;
  const int lane = tid & 63;
  const int wave = tid >> 6;     // 0..7

  const float* p = pts + (size_t)b * NPTS * 3;

  float px[PPT], py[PPT], pz[PPT], md[PPT];
#pragma unroll
  for (int i = 0; i < PPT; ++i) {
    const int n = w * (TPB * PPT) + i * TPB + tid;
    px[i] = p[3 * n + 0];
    py[i] = p[3 * n + 1];
    pz[i] = p[3 * n + 2];
    md[i] = 1e10f;               // BIG, matches reference init
  }

  float cx = p[0], cy = p[1], cz = p[2];   // first pick is index 0

  // ws (ull): [0..2048)     copy L (sc0): batch b at b*256, 2 par x 8 wg x 16
  //           [2048..4096)  copy I (agent/IF): same layout. 32 KiB total.
  ull* baseL = ws + (size_t)b * (2 * WPB * RECQ);
  ull* baseI = ws + (size_t)NB * (2 * WPB * RECQ) + (size_t)b * (2 * WPB * RECQ);

  float* out_idx = out + (size_t)b * NSAMP;
  float* out_smp = out + (size_t)NB * NSAMP + (size_t)b * NSAMP * 3;

  if (w == 0 && tid == 0) {
    out_idx[0] = 0.0f;
    out_smp[0] = cx; out_smp[1] = cy; out_smp[2] = cz;
  }

  __shared__ unsigned red[NWAVE][5];  // per-wave {dist_bits, n, x, y, z}; stride 5
                                      // -> banks (e*5)%32 distinct for e<8
  __shared__ float4 bc4;              // winner xyz (single b128 broadcast)
  __shared__ int bn2;                 // winner index

  bool useIF = false;                 // permanent fallback to IF polling

  for (int t = 0; t < NSAMP - 1; ++t) {
    // ---- local distance update + thread-local best (value+index only) ----
    float bv = -1.0f; int bi = 0;
#pragma unroll
    for (int i = 0; i < PPT; ++i) {
      const float dx = __fsub_rn(px[i], cx);
      const float dy = __fsub_rn(py[i], cy);
      const float dz = __fsub_rn(pz[i], cz);
      const float d  = __fadd_rn(__fadd_rn(__fmul_rn(dx, dx), __fmul_rn(dy, dy)),
                                 __fmul_rn(dz, dz));
      const float m = fminf(md[i], d);
      md[i] = m;
      if (m > bv) { bv = m; bi = i; }  // strict > keeps earliest i on ties
    }

    // ---- stage1: DPP wave64 max + ballot argmax ----
    const unsigned dbits = __float_as_uint(bv);   // bv>=0: bits order as uint
    const unsigned mw = umax_wave64(dbits);
    const bool tied = (dbits == mw);
    const ull bal0 = __ballot(tied);
    int wlane;
    if (__popcll(bal0) == 1) {
      wlane = __ffsll(bal0) - 1;
    } else {
      // exact first-occurrence: smallest (bi, lane) among tied lanes
      ull sel = 0;
#pragma unroll
      for (int ii = 0; ii < PPT; ++ii) {
        const ull bb = __ballot(tied && (bi == ii));
        const bool take = (sel == 0) && (bb != 0);
        sel = take ? bb : sel;
      }
      wlane = __ffsll(sel) - 1;
    }
    if (lane == wlane) {
      // recover xyz of point bi via compile-time-indexed select chain
      // (rule: no runtime array indexing -> stays in registers)
      float qx = px[0], qy = py[0], qz = pz[0];
#pragma unroll
      for (int ii = 1; ii < PPT; ++ii) {
        if (bi == ii) { qx = px[ii]; qy = py[ii]; qz = pz[ii]; }
      }
      red[wave][0] = dbits;
      red[wave][1] = (unsigned)(w * (TPB * PPT) + bi * TPB + tid);
      red[wave][2] = __float_as_uint(qx);
      red[wave][3] = __float_as_uint(qy);
      red[wave][4] = __float_as_uint(qz);
    }
    __syncthreads();  // barrier1 (8 waves; full drain — orders slot reuse)

    const ull tag = (ull)(unsigned)(t + 1);   // 1..1023; stale/poison never matches
    const int par = t & 1;

    if (wave == 1) {
      // ---- publisher: stage2, sc0 publish, agent-scope IF mirror ----
      ull w0, w1, w2; int ewin;
      stage2_pack(red, lane, tag, w0, w1, w2, ewin);
      if (lane == ewin) {
        const size_t so = (size_t)(par * WPB + w) * RECQ;
        st3_sc0(baseL + so, w0, w1, w2);
        ull* recI = baseI + so;
        __hip_atomic_store(recI + 0, w0, __ATOMIC_RELAXED, __HIP_MEMORY_SCOPE_AGENT);
        __hip_atomic_store(recI + 1, w1, __ATOMIC_RELAXED, __HIP_MEMORY_SCOPE_AGENT);
        __hip_atomic_store(recI + 2, w2, __ATOMIC_RELAXED, __HIP_MEMORY_SCOPE_AGENT);
      }
    } else if (wave == 0) {
      // ---- poller: lanes 0..7 each own one record ----
      const bool mine = (lane < WPB);
      const size_t roff = (size_t)(par * WPB + (lane & 7)) * RECQ;
      const ull* recL = baseL + roff;
      const ull* recI = baseI + roff;
      ull r0 = 0, r1 = 0, r2 = 0;
      bool s = !mine;     // per-lane success of the fast path

      if (!useIF) {
        // ---- pipelined sc0 poll: two 3-load sets in flight ----
        if (mine) {
          ull a0, a1, a2, b0, b1, b2;
          bool fromA = true, hit = false;
          ld3_issue(recL, a0, a1, a2);
          for (int it = 0; it < 128; ++it) {
            ld3_issue(recL, b0, b1, b2);
            wait3_touch(a0, a1, a2);          // A landed (B in flight)
            bool m = ((a0 & 0xFFFFull) == tag) & ((a1 & 0xFFFFull) == tag) &
                     ((a2 & 0xFFFFull) == tag);
            if (__all(m)) { hit = true; fromA = true; break; }
            ld3_issue(recL, a0, a1, a2);
            wait3_touch(b0, b1, b2);          // B landed (A in flight)
            m = ((b0 & 0xFFFFull) == tag) & ((b1 & 0xFFFFull) == tag) &
                ((b2 & 0xFFFFull) == tag);
            if (__all(m)) { hit = true; fromA = false; break; }
          }
          wait_vm0();                         // drain strays before reg reuse
          if (hit) {
            if (fromA) { r0 = a0; r1 = a1; r2 = a2; }
            else       { r0 = b0; r1 = b1; r2 = b2; }
            s = true;
          }
        }
      }

      if (!__all(s)) {
        // ---- slow path: agent-scope IF polling (placement-independent) ----
        useIF = true;                          // uniform: all lanes set it
        bool done = !mine;
        for (;;) {
          if (!done) {
            r0 = __hip_atomic_load(recI + 0, __ATOMIC_RELAXED, __HIP_MEMORY_SCOPE_AGENT);
            r1 = __hip_atomic_load(recI + 1, __ATOMIC_RELAXED, __HIP_MEMORY_SCOPE_AGENT);
            r2 = __hip_atomic_load(recI + 2, __ATOMIC_RELAXED, __HIP_MEMORY_SCOPE_AGENT);
            done = ((r0 & 0xFFFFull) == tag) & ((r1 & 0xFFFFull) == tag) &
                   ((r2 & 0xFFFFull) == tag);
          }
          if (__all(done)) break;
          __builtin_amdgcn_s_sleep(1);
        }
      }

      // ---- stage3: low8 DPP max + masked ballots over the 8 records ----
      const unsigned d3  = (unsigned)(r0 >> 32);                 // dist bits
      const unsigned lnv = (unsigned)((r0 >> 16) & 0xFFFFull);   // 65535-n
      const unsigned m3 = umax_low8(d3);
      const ull b3 = __ballot(d3 == m3) & 0xFFull;
      int src;
      if (__popcll(b3) == 1) {
        src = __ffsll(b3) - 1;
      } else {
        const unsigned v = (d3 == m3) ? lnv : 0u;                // max -> smallest n
        const unsigned mv = umax_low8(v);
        const ull b4 = __ballot((d3 == m3) && (v == mv)) & 0xFFull;
        src = __ffsll(b4) - 1;
      }
      const float xx = __uint_as_float((unsigned)(r1 >> 32));
      const float yy = __uint_as_float(((unsigned)((r1 >> 16) & 0xFFFFull) << 16) |
                                       (unsigned)(r2 >> 48));
      const float zz = __uint_as_float((unsigned)((r2 >> 16) & 0xFFFFFFFFull));
      const int n2   = 65535 - (int)__shfl((int)lnv, src, 64);
      const float wx = __shfl(xx, src, 64);
      const float wy = __shfl(yy, src, 64);
      const float wz = __shfl(zz, src, 64);
      if (lane == 0) {
        bc4 = make_float4(wx, wy, wz, 0.0f);   // single ds_write_b128
        bn2 = n2;
      }
    }
    __syncthreads();  // barrier2 (wave0 has no outstanding stores here)

    // ---- deferred output store (off the critical path) ----
    const float4 c4 = bc4;                     // single ds_read_b128
    if (w == 0 && wave == 2 && lane == 0) {
      out_idx[t + 1] = (float)bn2;             // exact in fp32
      out_smp[(t + 1) * 3 + 0] = c4.x;
      out_smp[(t + 1) * 3 + 1] = c4.y;
      out_smp[(t + 1) * 3 + 2] = c4.z;
    }
    cx = c4.x; cy = c4.y; cz = c4.z;
  }
}

extern "C" void kernel_launch(void* const* d_in, const int* in_sizes, int n_in,
                              void* d_out, int out_size, void* d_ws, size_t ws_size,
                              hipStream_t stream) {
  (void)in_sizes; (void)n_in; (void)out_size; (void)ws_size;
  const float* pts = (const float*)d_in[0];
  float* out = (float*)d_out;
  ull* ws = (ull*)d_ws;
  fps_kernel<<<dim3(NB * WPB), dim3(TPB), 0, stream>>>(pts, out, ws);
}

// Round 6
// 2406.166 us; speedup vs baseline: 1.1395x; 1.1395x over previous
//
#include <hip/hip_runtime.h>

// FPS: input [8, 65536, 3] f32 -> (idx [8,1024] as f32 values, sampled [8,1024,3] f32)
// concatenated flat in d_out.
//
// R20 = R14 proven protocol (WPB=32 x TPB=512 x PPT=4 — R19 proved this
// geometry right; sc0 publish + agent-IF mirror; 128B AoS records; sticky IF
// fallback; DPP reduces) with the sync overhead around the fixed IF round
// trip cut three ways:
//  1. barrier1 ELIMINATED: last-arriving wave publishes. Each wave writes
//     red[par][wave], lgkmcnt(0), then ds_add on cnt[par]; the wave seeing
//     old==7 runs stage2+publish IMMEDIATELY (publish starts at slowest-wave
//     data-ready instead of after barrier release + wave1 wakeup). The one
//     remaining __syncthreads (bottom) fully drains vmcnt — its drain is off
//     the critical path (the poller arrives last), and it provides the same
//     publish(t) < publish(t+2) slot-reuse ordering barrier1 used to.
//     lgkmcnt(0) between red-write and counter-add makes cross-wave LDS
//     visibility airtight (write COMPLETED before add counted).
//  2. 4-deep poll pipeline (sets A-D), ISSUED EARLY at loop top: pipeline
//     is warm by publish time (dist is pure-register VALU, no vmcnt
//     interference); check granularity rt/4 instead of rt/2.
//  3. dual-lane publish: lane ewin -> 3 sc0 stores, lane ewin+8 (same
//     stage2 words) -> 3 IF-mirror stores, in parallel.
//
// R19 post-mortem: fan-in width was NOT the cost (narrowing 4x saved zero;
// bigger PPT added ~1350cy VALU). R15-R18: wider polling, shared-line
// layouts, plain-store tier, atomic-read tier all regressed or died.
// The residual after the exchange round trip is sync overhead — this round
// attacks exactly that.
//
// Correctness invariants (unchanged from R14):
//  - Ties resolve to smallest global index; distances uncontracted fp32 in
//    reference order -> bit-exact.
//  - Records: 3x 8B self-tagged words (tag in low16), parity double-buffered;
//    stale/poison (0xAAAA) never matches; per-word tags make mixed-age words
//    harmless. Slot reuse t vs t+2 ordered via the full-drain barrier.
//  - bc4/bn2 single-buffered: write(t+1) is causally after all waves' reads
//    of bc4(t) (write(t+1) <= detect(t+1) <= own publish(t+1) <= all adds(t+1)
//    <= all bc4(t) reads).
//  - IF fallback (wave-uniform, sticky) keeps correctness independent of
//    block->XCD placement.

#define NB    8
#define NPTS  65536
#define NSAMP 1024
#define WPB   32     // workgroups per batch (one XCD at 256 blocks)
#define TPB   512    // threads per workgroup (8 waves)
#define NWAVE 8
#define PPT   4      // points per thread (WPB*TPB*PPT == NPTS)
#define RECQ  16     // 16 ull = 128 B per record line

typedef unsigned long long ull;

#define DPP(x, ctrl) \
  ((unsigned)__builtin_amdgcn_update_dpp((int)(x), (int)(x), (ctrl), 0xf, 0xf, false))

// max over 64 lanes -> uniform; row_shr:N = 0x110|N, bcast15=0x142, bcast31=0x143
__device__ __forceinline__ unsigned umax_wave64(unsigned x) {
  unsigned t;
  t = DPP(x, 0x111); x = t > x ? t : x;
  t = DPP(x, 0x112); x = t > x ? t : x;
  t = DPP(x, 0x114); x = t > x ? t : x;
  t = DPP(x, 0x118); x = t > x ? t : x;
  t = DPP(x, 0x142); x = t > x ? t : x;   // bcast15: row r lane15 -> row r+1
  t = DPP(x, 0x143); x = t > x ? t : x;   // bcast31: lane31 -> rows 2,3
  return (unsigned)__builtin_amdgcn_readlane((int)x, 63);
}
// max over lanes 0..7 -> uniform via lane7 (groups of 16 see their row's shr)
__device__ __forceinline__ unsigned umax_low8(unsigned x) {
  unsigned t;
  t = DPP(x, 0x111); x = t > x ? t : x;
  t = DPP(x, 0x112); x = t > x ? t : x;
  t = DPP(x, 0x114); x = t > x ? t : x;
  return (unsigned)__builtin_amdgcn_readlane((int)x, 7);
}

// 3x 8B loads, NO waitcnt (pipelined polling: caller manages vmcnt).
__device__ __forceinline__ void ld3_issue(const ull* p, ull& a, ull& b, ull& c) {
  asm volatile(
      "global_load_dwordx2 %0, %3, off sc0\n\t"
      "global_load_dwordx2 %1, %3, off offset:8 sc0\n\t"
      "global_load_dwordx2 %2, %3, off offset:16 sc0"
      : "=&v"(a), "=&v"(b), "=&v"(c) : "v"(p) : "memory");
}
// wait until <=9 ops outstanding (oldest 3-load set of 4 landed).
__device__ __forceinline__ void wait9_touch(ull& a, ull& b, ull& c) {
  asm volatile("s_waitcnt vmcnt(9)" : "+v"(a), "+v"(b), "+v"(c) :: "memory");
}
__device__ __forceinline__ void wait_vm0() {
  asm volatile("s_waitcnt vmcnt(0)" ::: "memory");
}
// 3x 8B stores, fire-and-forget (write-through to coherence point).
__device__ __forceinline__ void st3_sc0(ull* p, ull a, ull b, ull c) {
  asm volatile(
      "global_store_dwordx2 %3, %0, off sc0\n\t"
      "global_store_dwordx2 %3, %1, off offset:8 sc0\n\t"
      "global_store_dwordx2 %3, %2, off offset:16 sc0"
      :: "v"(a), "v"(b), "v"(c), "v"(p) : "memory");
}

__device__ __forceinline__ bool tag3(ull a, ull b, ull c, ull tag) {
  return ((a & 0xFFFFull) == tag) & ((b & 0xFFFFull) == tag) &
         ((c & 0xFFFFull) == tag);
}

// stage2: select WG winner from red[8][5]; packed words + winning lane
__device__ __forceinline__ void stage2_pack(const unsigned (*red)[5], int lane,
                                            ull tag, ull& w0, ull& w1, ull& w2,
                                            int& ewin) {
  const int e = lane & 7;
  const unsigned d2 = red[e][0];
  const unsigned nn = red[e][1];
  const unsigned mx = umax_low8(d2);
  const ull bb = __ballot(d2 == mx) & 0xFFull;
  if (__popcll(bb) == 1) {
    ewin = __ffsll(bb) - 1;
  } else {
    const unsigned v = (d2 == mx) ? (65535u - nn) : 0u;   // max -> smallest n
    const unsigned mv = umax_low8(v);
    const ull b2 = __ballot((d2 == mx) && (v == mv)) & 0xFFull;
    ewin = __ffsll(b2) - 1;
  }
  const ull k2 = ((ull)d2 << 16) | (ull)(65535u - nn);
  const unsigned xb = red[e][2], yb = red[e][3], zb = red[e][4];
  w0 = (k2 << 16) | tag;
  w1 = ((ull)xb << 32) | ((ull)(yb >> 16) << 16) | tag;
  w2 = ((ull)(yb & 0xFFFFu) << 48) | ((ull)zb << 16) | tag;
}

__global__ __launch_bounds__(TPB, 4)
void fps_kernel(const float* __restrict__ pts, float* __restrict__ out,
                ull* __restrict__ ws) {
  const int wg   = blockIdx.x;   // 0..255
  const int b    = wg >> 5;      // batch: CONTIGUOUS blocks 32b..32b+31 (one XCD)
  const int w    = wg & 31;      // wg within batch, 0..31
  const int tid  = threadIdx.x;
  const int lane = tid & 63;
  const int wave = tid >> 6;     // 0..7

  const float* p = pts + (size_t)b * NPTS * 3;

  float px[PPT], py[PPT], pz[PPT], md[PPT];
#pragma unroll
  for (int i = 0; i < PPT; ++i) {
    const int n = w * (TPB * PPT) + i * TPB + tid;
    px[i] = p[3 * n + 0];
    py[i] = p[3 * n + 1];
    pz[i] = p[3 * n + 2];
    md[i] = 1e10f;               // BIG, matches reference init
  }

  float cx = p[0], cy = p[1], cz = p[2];   // first pick is index 0

  // ws (ull): [0..8192)     copy L (sc0/L2): batch b at b*1024, 2 par x 32 wg x 16
  //           [8192..16384) copy I (agent/IF): same layout. 128 KiB total.
  ull* baseL = ws + (size_t)b * (2 * WPB * RECQ);
  ull* baseI = ws + (size_t)NB * (2 * WPB * RECQ) + (size_t)b * (2 * WPB * RECQ);

  float* out_idx = out + (size_t)b * NSAMP;
  float* out_smp = out + (size_t)NB * NSAMP + (size_t)b * NSAMP * 3;

  if (w == 0 && tid == 0) {
    out_idx[0] = 0.0f;
    out_smp[0] = cx; out_smp[1] = cy; out_smp[2] = cz;
  }

  __shared__ unsigned red[2][NWAVE][5]; // parity x wave {dist_bits,n,x,y,z}
  __shared__ unsigned cnt[2];           // parity arrival counters
  __shared__ float4 bc4;                // winner xyz (single b128 broadcast)
  __shared__ int bn2;                   // winner index

  if (tid == 0) { cnt[0] = 0u; cnt[1] = 0u; }
  __syncthreads();

  bool useIF = false;                 // permanent fallback to IF polling
  // 4-deep poll pipeline registers (live across iteration top -> poll phase)
  ull A0 = 0, A1 = 0, A2 = 0, B0 = 0, B1 = 0, B2 = 0;
  ull C0 = 0, C1 = 0, C2 = 0, D0 = 0, D1 = 0, D2 = 0;

  for (int t = 0; t < NSAMP - 1; ++t) {
    const ull tag = (ull)(unsigned)(t + 1);   // 1..1023; 0xAAAA poison never matches
    const int par = t & 1;
    const size_t roff = (size_t)(par * WPB + (lane & 31)) * RECQ;

    // ---- wave0: issue 4 poll sets EARLY (warm pipeline; dist below is
    //      pure-register VALU so no vmcnt interference) ----
    if (wave == 0 && !useIF && lane < WPB) {
      const ull* recL = baseL + roff;
      ld3_issue(recL, A0, A1, A2);
      ld3_issue(recL, B0, B1, B2);
      ld3_issue(recL, C0, C1, C2);
      ld3_issue(recL, D0, D1, D2);
    }

    // ---- local distance update + thread-local best (value+index only) ----
    float bv = -1.0f; int bi = 0;
#pragma unroll
    for (int i = 0; i < PPT; ++i) {
      const float dx = __fsub_rn(px[i], cx);
      const float dy = __fsub_rn(py[i], cy);
      const float dz = __fsub_rn(pz[i], cz);
      const float d  = __fadd_rn(__fadd_rn(__fmul_rn(dx, dx), __fmul_rn(dy, dy)),
                                 __fmul_rn(dz, dz));
      const float m = fminf(md[i], d);
      md[i] = m;
      if (m > bv) { bv = m; bi = i; }  // strict > keeps earliest i on ties
    }

    // ---- stage1: DPP wave64 max + ballot argmax ----
    const unsigned dbits = __float_as_uint(bv);   // bv>=0: bits order as uint
    const unsigned mw = umax_wave64(dbits);
    const bool tied = (dbits == mw);
    const ull bal0 = __ballot(tied);
    int wlane;
    if (__popcll(bal0) == 1) {
      wlane = __ffsll(bal0) - 1;
    } else {
      // exact first-occurrence: smallest (bi, lane) among tied lanes
      ull sel = 0;
#pragma unroll
      for (int ii = 0; ii < PPT; ++ii) {
        const ull bb = __ballot(tied && (bi == ii));
        const bool take = (sel == 0) && (bb != 0);
        sel = take ? bb : sel;
      }
      wlane = __ffsll(sel) - 1;
    }
    if (lane == wlane) {
      // recover xyz of point bi via cndmask tree (only this lane pays)
      const bool c1 = (bi & 1), c2 = (bi & 2);
      const float qx = c2 ? (c1 ? px[3] : px[2]) : (c1 ? px[1] : px[0]);
      const float qy = c2 ? (c1 ? py[3] : py[2]) : (c1 ? py[1] : py[0]);
      const float qz = c2 ? (c1 ? pz[3] : pz[2]) : (c1 ? pz[1] : pz[0]);
      red[par][wave][0] = dbits;
      red[par][wave][1] = (unsigned)(w * (TPB * PPT) + bi * TPB + tid);
      red[par][wave][2] = __float_as_uint(qx);
      red[par][wave][3] = __float_as_uint(qy);
      red[par][wave][4] = __float_as_uint(qz);
    }
    // red-write COMPLETE before the arrival add is visible (cross-wave
    // publish safety; lgkmcnt(0) = completion, not just issue order)
    asm volatile("s_waitcnt lgkmcnt(0)" ::: "memory");

    // ---- arrival counter: the 8th (last) wave publishes immediately ----
    unsigned old0 = 0;
    if (lane == 0) old0 = atomicAdd(&cnt[par], 1u);
    old0 = (unsigned)__shfl((int)old0, 0, 64);

    if (old0 == 7u) {
      // ---- publisher = last-arriving wave: stage2, dual-lane publish ----
      ull w0, w1, w2; int ewin;
      stage2_pack(red[par], lane, tag, w0, w1, w2, ewin);
      const size_t so = (size_t)(par * WPB + w) * RECQ;
      if (lane == ewin) {
        st3_sc0(baseL + so, w0, w1, w2);        // sc0/L2 publish
      }
      if (lane == ewin + 8) {                   // same e -> same words
        ull* recI = baseI + so;                 // agent-scope IF mirror
        __hip_atomic_store(recI + 0, w0, __ATOMIC_RELAXED, __HIP_MEMORY_SCOPE_AGENT);
        __hip_atomic_store(recI + 1, w1, __ATOMIC_RELAXED, __HIP_MEMORY_SCOPE_AGENT);
        __hip_atomic_store(recI + 2, w2, __ATOMIC_RELAXED, __HIP_MEMORY_SCOPE_AGENT);
      }
      if (lane == 0) cnt[par ^ 1] = 0u;         // reset other parity for t+1
    }

    if (wave == 0) {
      // ---- poller: 4-deep ring check over the 32 records ----
      const bool mine = (lane < WPB);
      const ull* recL = baseL + roff;
      const ull* recI = baseI + roff;
      ull r0 = 0, r1 = 0, r2 = 0;
      bool s = !mine;     // per-lane success of the fast path

      if (!useIF) {
        if (mine) {
          bool hit = false; int from = 0;
          for (int it = 0; it < 96; ++it) {
            wait9_touch(A0, A1, A2);
            if (__all(tag3(A0, A1, A2, tag))) { hit = true; from = 0; break; }
            ld3_issue(recL, A0, A1, A2);
            wait9_touch(B0, B1, B2);
            if (__all(tag3(B0, B1, B2, tag))) { hit = true; from = 1; break; }
            ld3_issue(recL, B0, B1, B2);
            wait9_touch(C0, C1, C2);
            if (__all(tag3(C0, C1, C2, tag))) { hit = true; from = 2; break; }
            ld3_issue(recL, C0, C1, C2);
            wait9_touch(D0, D1, D2);
            if (__all(tag3(D0, D1, D2, tag))) { hit = true; from = 3; break; }
            ld3_issue(recL, D0, D1, D2);
          }
          wait_vm0();                         // drain strays before reg reuse
          if (hit) {
            if (from == 0)      { r0 = A0; r1 = A1; r2 = A2; }
            else if (from == 1) { r0 = B0; r1 = B1; r2 = B2; }
            else if (from == 2) { r0 = C0; r1 = C1; r2 = C2; }
            else                { r0 = D0; r1 = D1; r2 = D2; }
            s = true;
          }
        }
      }

      if (!__all(s)) {
        // ---- slow path: agent-scope IF polling (placement-independent) ----
        useIF = true;                          // uniform: all lanes set it
        bool done = !mine;
        for (;;) {
          if (!done) {
            r0 = __hip_atomic_load(recI + 0, __ATOMIC_RELAXED, __HIP_MEMORY_SCOPE_AGENT);
            r1 = __hip_atomic_load(recI + 1, __ATOMIC_RELAXED, __HIP_MEMORY_SCOPE_AGENT);
            r2 = __hip_atomic_load(recI + 2, __ATOMIC_RELAXED, __HIP_MEMORY_SCOPE_AGENT);
            done = tag3(r0, r1, r2, tag);
          }
          if (__all(done)) break;
          __builtin_amdgcn_s_sleep(1);
        }
      }

      // ---- stage3: full wave64 DPP max + ballot over 32 records (hi lanes
      //      hold zeros -> never win; value-based n-tie ballots safe) ----
      const unsigned d3  = (unsigned)(r0 >> 32);                 // dist bits
      const unsigned lnv = (unsigned)((r0 >> 16) & 0xFFFFull);   // 65535-n
      const unsigned m3 = umax_wave64(d3);
      const ull b3 = __ballot(d3 == m3);
      int src;
      if (__popcll(b3) == 1) {
        src = __ffsll(b3) - 1;
      } else {
        const unsigned v = (d3 == m3) ? lnv : 0u;                // max -> smallest n
        const unsigned mv = umax_wave64(v);
        const ull b4 = __ballot((d3 == m3) && (v == mv));
        src = __ffsll(b4) - 1;
      }
      const float xx = __uint_as_float((unsigned)(r1 >> 32));
      const float yy = __uint_as_float(((unsigned)((r1 >> 16) & 0xFFFFull) << 16) |
                                       (unsigned)(r2 >> 48));
      const float zz = __uint_as_float((unsigned)((r2 >> 16) & 0xFFFFFFFFull));
      const int n2   = 65535 - (int)__shfl((int)lnv, src, 64);
      const float wx = __shfl(xx, src, 64);
      const float wy = __shfl(yy, src, 64);
      const float wz = __shfl(zz, src, 64);
      if (lane == 0) {
        bc4 = make_float4(wx, wy, wz, 0.0f);   // single ds_write_b128
        bn2 = n2;
      }
    }
    // The ONLY barrier: full drain (vmcnt+lgkm). Drain is off the critical
    // path (poller arrives last); provides publish(t) < publish(t+2) slot
    // ordering and bc4 visibility.
    __syncthreads();

    // ---- deferred output store (off the critical path) ----
    const float4 c4 = bc4;                     // single ds_read_b128
    if (w == 0 && wave == 2 && lane == 0) {
      out_idx[t + 1] = (float)bn2;             // exact in fp32
      out_smp[(t + 1) * 3 + 0] = c4.x;
      out_smp[(t + 1) * 3 + 1] = c4.y;
      out_smp[(t + 1) * 3 + 2] = c4.z;
    }
    cx = c4.x; cy = c4.y; cz = c4.z;
  }
}

extern "C" void kernel_launch(void* const* d_in, const int* in_sizes, int n_in,
                              void* d_out, int out_size, void* d_ws, size_t ws_size,
                              hipStream_t stream) {
  (void)in_sizes; (void)n_in; (void)out_size; (void)ws_size;
  const float* pts = (const float*)d_in[0];
  float* out = (float*)d_out;
  ull* ws = (ull*)d_ws;
  fps_kernel<<<dim3(NB * WPB), dim3(TPB), 0, stream>>>(pts, out, ws);
}

// Round 7
// 2136.002 us; speedup vs baseline: 1.2836x; 1.1265x over previous
//
#include <hip/hip_runtime.h>

// FPS: input [8, 65536, 3] f32 -> (idx [8,1024] as f32 values, sampled [8,1024,3] f32)
// concatenated flat in d_out.
//
// R21 = R14 EXACT (session-best, 2140.2us verified): two barriers; wave1
// publisher -> sc0/L2 copy + agent-scope IF mirror; wave0 pipelined-polls
// w/ IF fallback; deferred output store; DPP reduces; conflict-free
// red[][5]; 32 WGs/batch x 512 thr x 4 pts/thread (256 blocks = 1 WG/CU,
// 8 waves).
//
// Session post-mortem (R15-R20, all regressed vs this structure):
//  - R15 (+1400us): 8 polling waves octupled sc0 request rate on hot lines.
//  - R16 (+630us): SoA shared-line exchange serialized publishers vs polls.
//  - R17 (+500us): plain-store/L2 tier is marginal (sc0 loads are device-
//    scope, route past XCD L2 -> oscillating timeout).
//  - R18 (died): atomic-read exchange killed the container.
//  - R19 (+570us): fan-in width was never the cost; PPT=16 added ~1300cy
//    VALU to the critical path.
//  - R20 (+280us): LDS-counter handshake costs MORE than s_barrier's HW
//    release; deep/early polling checks in bursts (no staleness gain).
// Bottleneck: 1023 serial cross-WG rendezvous, each pinned at the IF
// visibility round trip (~2000+cy). HBM 1%, VALU 14% — a latency floor,
// not a counter roofline; this geometry is the measured optimum.
//
// Ties resolve to the smallest global index (numpy argmax first-occurrence);
// distances are uncontracted fp32 in reference order -> bit-exact.
// Records: 3x 8B self-tagged words (round tag in low16 of each), parity
// double-buffered; stale L2 lines can't fake a future tag; per-word tags
// make mixed-age words harmless. Slot reuse at t+2 ordered by tag
// transitivity through barrier2. IF fallback (wave-uniform, 128-double-iter
// timeout) keeps correctness independent of block->XCD placement.

#define NB    8
#define NPTS  65536
#define NSAMP 1024
#define WPB   32     // workgroups per batch (one XCD at 256 blocks)
#define TPB   512    // threads per workgroup (8 waves)
#define NWAVE 8
#define PPT   4      // points per thread (WPB*TPB*PPT == NPTS)
#define RECQ  16     // 16 ull = 128 B per record line

typedef unsigned long long ull;

#define DPP(x, ctrl) \
  ((unsigned)__builtin_amdgcn_update_dpp((int)(x), (int)(x), (ctrl), 0xf, 0xf, false))

// max over 64 lanes -> uniform; row_shr:N = 0x110|N, bcast15=0x142, bcast31=0x143
__device__ __forceinline__ unsigned umax_wave64(unsigned x) {
  unsigned t;
  t = DPP(x, 0x111); x = t > x ? t : x;
  t = DPP(x, 0x112); x = t > x ? t : x;
  t = DPP(x, 0x114); x = t > x ? t : x;
  t = DPP(x, 0x118); x = t > x ? t : x;
  t = DPP(x, 0x142); x = t > x ? t : x;   // bcast15: row r lane15 -> row r+1
  t = DPP(x, 0x143); x = t > x ? t : x;   // bcast31: lane31 -> rows 2,3
  return (unsigned)__builtin_amdgcn_readlane((int)x, 63);
}
// max over lanes 0..7 -> uniform via lane7 (groups of 16 see their row's shr)
__device__ __forceinline__ unsigned umax_low8(unsigned x) {
  unsigned t;
  t = DPP(x, 0x111); x = t > x ? t : x;
  t = DPP(x, 0x112); x = t > x ? t : x;
  t = DPP(x, 0x114); x = t > x ? t : x;
  return (unsigned)__builtin_amdgcn_readlane((int)x, 7);
}

// 3x 8B loads, NO waitcnt (pipelined polling: caller manages vmcnt).
__device__ __forceinline__ void ld3_issue(const ull* p, ull& a, ull& b, ull& c) {
  asm volatile(
      "global_load_dwordx2 %0, %3, off sc0\n\t"
      "global_load_dwordx2 %1, %3, off offset:8 sc0\n\t"
      "global_load_dwordx2 %2, %3, off offset:16 sc0"
      : "=&v"(a), "=&v"(b), "=&v"(c) : "v"(p) : "memory");
}
// wait until <=3 loads outstanding; data threaded via "+v" for SSA ordering.
__device__ __forceinline__ void wait3_touch(ull& a, ull& b, ull& c) {
  asm volatile("s_waitcnt vmcnt(3)" : "+v"(a), "+v"(b), "+v"(c) :: "memory");
}
__device__ __forceinline__ void wait_vm0() {
  asm volatile("s_waitcnt vmcnt(0)" ::: "memory");
}
// 3x 8B stores, fire-and-forget (write-through to XCD L2).
__device__ __forceinline__ void st3_sc0(ull* p, ull a, ull b, ull c) {
  asm volatile(
      "global_store_dwordx2 %3, %0, off sc0\n\t"
      "global_store_dwordx2 %3, %1, off offset:8 sc0\n\t"
      "global_store_dwordx2 %3, %2, off offset:16 sc0"
      :: "v"(a), "v"(b), "v"(c), "v"(p) : "memory");
}

// stage2: select WG winner from red[8][5]; packed words + winning lane
__device__ __forceinline__ void stage2_pack(const unsigned (*red)[5], int lane,
                                            ull tag, ull& w0, ull& w1, ull& w2,
                                            int& ewin) {
  const int e = lane & 7;
  const unsigned d2 = red[e][0];
  const unsigned nn = red[e][1];
  const unsigned mx = umax_low8(d2);
  const ull bb = __ballot(d2 == mx) & 0xFFull;
  if (__popcll(bb) == 1) {
    ewin = __ffsll(bb) - 1;
  } else {
    const unsigned v = (d2 == mx) ? (65535u - nn) : 0u;   // max -> smallest n
    const unsigned mv = umax_low8(v);
    const ull b2 = __ballot((d2 == mx) && (v == mv)) & 0xFFull;
    ewin = __ffsll(b2) - 1;
  }
  const ull k2 = ((ull)d2 << 16) | (ull)(65535u - nn);
  const unsigned xb = red[e][2], yb = red[e][3], zb = red[e][4];
  w0 = (k2 << 16) | tag;
  w1 = ((ull)xb << 32) | ((ull)(yb >> 16) << 16) | tag;
  w2 = ((ull)(yb & 0xFFFFu) << 48) | ((ull)zb << 16) | tag;
}

__global__ __launch_bounds__(TPB, 4)
void fps_kernel(const float* __restrict__ pts, float* __restrict__ out,
                ull* __restrict__ ws) {
  const int wg   = blockIdx.x;   // 0..255
  const int b    = wg >> 5;      // batch: CONTIGUOUS blocks 32b..32b+31 (one XCD)
  const int w    = wg & 31;      // wg within batch, 0..31
  const int tid  = threadIdx.x;
  const int lane = tid & 63;
  const int wave = tid >> 6;     // 0..7

  const float* p = pts + (size_t)b * NPTS * 3;

  float px[PPT], py[PPT], pz[PPT], md[PPT];
#pragma unroll
  for (int i = 0; i < PPT; ++i) {
    const int n = w * (TPB * PPT) + i * TPB + tid;
    px[i] = p[3 * n + 0];
    py[i] = p[3 * n + 1];
    pz[i] = p[3 * n + 2];
    md[i] = 1e10f;               // BIG, matches reference init
  }

  float cx = p[0], cy = p[1], cz = p[2];   // first pick is index 0

  // ws (ull): [0..8192)     copy L (sc0/L2): batch b at b*1024, 2 par x 32 wg x 16
  //           [8192..16384) copy I (agent/IF): same layout. 128 KiB total.
  ull* baseL = ws + (size_t)b * (2 * WPB * RECQ);
  ull* baseI = ws + (size_t)NB * (2 * WPB * RECQ) + (size_t)b * (2 * WPB * RECQ);

  float* out_idx = out + (size_t)b * NSAMP;
  float* out_smp = out + (size_t)NB * NSAMP + (size_t)b * NSAMP * 3;

  if (w == 0 && tid == 0) {
    out_idx[0] = 0.0f;
    out_smp[0] = cx; out_smp[1] = cy; out_smp[2] = cz;
  }

  __shared__ unsigned red[NWAVE][5];  // per-wave {dist_bits, n, x, y, z}; stride 5
                                      // -> banks (e*5)%32 distinct for e<8
  __shared__ float4 bc4;              // winner xyz (single b128 broadcast)
  __shared__ int bn2;                 // winner index

  bool useIF = false;                 // permanent fallback to IF polling

  for (int t = 0; t < NSAMP - 1; ++t) {
    // ---- local distance update + thread-local best (value+index only) ----
    float bv = -1.0f; int bi = 0;
#pragma unroll
    for (int i = 0; i < PPT; ++i) {
      const float dx = __fsub_rn(px[i], cx);
      const float dy = __fsub_rn(py[i], cy);
      const float dz = __fsub_rn(pz[i], cz);
      const float d  = __fadd_rn(__fadd_rn(__fmul_rn(dx, dx), __fmul_rn(dy, dy)),
                                 __fmul_rn(dz, dz));
      const float m = fminf(md[i], d);
      md[i] = m;
      if (m > bv) { bv = m; bi = i; }  // strict > keeps earliest i on ties
    }

    // ---- stage1: DPP wave64 max + ballot argmax ----
    const unsigned dbits = __float_as_uint(bv);   // bv>=0: bits order as uint
    const unsigned mw = umax_wave64(dbits);
    const bool tied = (dbits == mw);
    const ull bal0 = __ballot(tied);
    int wlane;
    if (__popcll(bal0) == 1) {
      wlane = __ffsll(bal0) - 1;
    } else {
      // exact first-occurrence: smallest (bi, lane) among tied lanes
      ull sel = 0;
#pragma unroll
      for (int ii = 0; ii < PPT; ++ii) {
        const ull bb = __ballot(tied && (bi == ii));
        const bool take = (sel == 0) && (bb != 0);
        sel = take ? bb : sel;
      }
      wlane = __ffsll(sel) - 1;
    }
    if (lane == wlane) {
      // recover xyz of point bi via cndmask tree (only this lane pays)
      const bool c1 = (bi & 1), c2 = (bi & 2);
      const float qx = c2 ? (c1 ? px[3] : px[2]) : (c1 ? px[1] : px[0]);
      const float qy = c2 ? (c1 ? py[3] : py[2]) : (c1 ? py[1] : py[0]);
      const float qz = c2 ? (c1 ? pz[3] : pz[2]) : (c1 ? pz[1] : pz[0]);
      red[wave][0] = dbits;
      red[wave][1] = (unsigned)(w * (TPB * PPT) + bi * TPB + tid);
      red[wave][2] = __float_as_uint(qx);
      red[wave][3] = __float_as_uint(qy);
      red[wave][4] = __float_as_uint(qz);
    }
    __syncthreads();  // barrier1 (8 waves)

    const ull tag = (ull)(unsigned)(t + 1);   // 1..1023; 0xAAAA poison never matches
    const int par = t & 1;

    if (wave == 1) {
      // ---- publisher: stage2, sc0 publish (L2), IF mirror ----
      ull w0, w1, w2; int ewin;
      stage2_pack(red, lane, tag, w0, w1, w2, ewin);
      if (lane == ewin) {
        st3_sc0(baseL + (size_t)(par * WPB + w) * RECQ, w0, w1, w2);
        ull* recI = baseI + (size_t)(par * WPB + w) * RECQ;
        __hip_atomic_store(recI + 0, w0, __ATOMIC_RELAXED, __HIP_MEMORY_SCOPE_AGENT);
        __hip_atomic_store(recI + 1, w1, __ATOMIC_RELAXED, __HIP_MEMORY_SCOPE_AGENT);
        __hip_atomic_store(recI + 2, w2, __ATOMIC_RELAXED, __HIP_MEMORY_SCOPE_AGENT);
      }
    } else if (wave == 0) {
      const size_t roff = (size_t)(par * WPB + (lane & 31)) * RECQ;
      const ull* recL = baseL + roff;
      const ull* recI = baseI + roff;
      const bool mine = (lane < WPB);
      ull r0 = 0, r1 = 0, r2 = 0;
      bool s = !mine;     // per-lane success of the fast path

      if (!useIF) {
        // ---- pipelined sc0/L2 poll: two 3-load sets in flight ----
        if (mine) {
          ull a0, a1, a2, b0, b1, b2;
          bool fromA = true, hit = false;
          ld3_issue(recL, a0, a1, a2);
          for (int it = 0; it < 128; ++it) {
            ld3_issue(recL, b0, b1, b2);
            wait3_touch(a0, a1, a2);          // A landed (B in flight)
            bool m = ((a0 & 0xFFFFull) == tag) & ((a1 & 0xFFFFull) == tag) &
                     ((a2 & 0xFFFFull) == tag);
            if (__all(m)) { hit = true; fromA = true; break; }
            ld3_issue(recL, a0, a1, a2);
            wait3_touch(b0, b1, b2);          // B landed (A in flight)
            m = ((b0 & 0xFFFFull) == tag) & ((b1 & 0xFFFFull) == tag) &
                ((b2 & 0xFFFFull) == tag);
            if (__all(m)) { hit = true; fromA = false; break; }
          }
          wait_vm0();                         // drain strays before reg reuse
          if (hit) {
            if (fromA) { r0 = a0; r1 = a1; r2 = a2; }
            else       { r0 = b0; r1 = b1; r2 = b2; }
            s = true;
          }
        }
      }

      if (!__all(s)) {
        // ---- slow path: agent-scope IF polling (placement-independent) ----
        useIF = true;                          // uniform: all lanes set it
        bool done = !mine;
        for (;;) {
          if (!done) {
            r0 = __hip_atomic_load(recI + 0, __ATOMIC_RELAXED, __HIP_MEMORY_SCOPE_AGENT);
            r1 = __hip_atomic_load(recI + 1, __ATOMIC_RELAXED, __HIP_MEMORY_SCOPE_AGENT);
            r2 = __hip_atomic_load(recI + 2, __ATOMIC_RELAXED, __HIP_MEMORY_SCOPE_AGENT);
            done = ((r0 & 0xFFFFull) == tag) & ((r1 & 0xFFFFull) == tag) &
                   ((r2 & 0xFFFFull) == tag);
          }
          if (__all(done)) break;
          __builtin_amdgcn_s_sleep(1);
        }
      }

      // ---- stage3: full wave64 DPP max + ballot over 32 records (lanes
      //      32..63 duplicate 0..31 -> ffs picks the lower; value-based
      //      n-tie ballots are duplicate-safe) ----
      const unsigned d3  = (unsigned)(r0 >> 32);                 // dist bits
      const unsigned lnv = (unsigned)((r0 >> 16) & 0xFFFFull);   // 65535-n
      const unsigned m3 = umax_wave64(d3);
      const ull b3 = __ballot(d3 == m3);
      int src;
      if (__popcll(b3) == 1) {
        src = __ffsll(b3) - 1;
      } else {
        const unsigned v = (d3 == m3) ? lnv : 0u;                // max -> smallest n
        const unsigned mv = umax_wave64(v);
        const ull b4 = __ballot((d3 == m3) && (v == mv));
        src = __ffsll(b4) - 1;
      }
      const float xx = __uint_as_float((unsigned)(r1 >> 32));
      const float yy = __uint_as_float(((unsigned)((r1 >> 16) & 0xFFFFull) << 16) |
                                       (unsigned)(r2 >> 48));
      const float zz = __uint_as_float((unsigned)((r2 >> 16) & 0xFFFFFFFFull));
      const int n2   = 65535 - (int)__shfl((int)lnv, src, 64);
      const float wx = __shfl(xx, src, 64);
      const float wy = __shfl(yy, src, 64);
      const float wz = __shfl(zz, src, 64);
      if (lane == 0) {
        bc4 = make_float4(wx, wy, wz, 0.0f);   // single ds_write_b128
        bn2 = n2;
      }
    }
    __syncthreads();  // barrier2 (wave0 has no outstanding stores here)

    // ---- deferred output store (off the critical path) ----
    const float4 c4 = bc4;                     // single ds_read_b128
    if (w == 0 && wave == 2 && lane == 0) {
      out_idx[t + 1] = (float)bn2;             // exact in fp32
      out_smp[(t + 1) * 3 + 0] = c4.x;
      out_smp[(t + 1) * 3 + 1] = c4.y;
      out_smp[(t + 1) * 3 + 2] = c4.z;
    }
    cx = c4.x; cy = c4.y; cz = c4.z;
  }
}

extern "C" void kernel_launch(void* const* d_in, const int* in_sizes, int n_in,
                              void* d_out, int out_size, void* d_ws, size_t ws_size,
                              hipStream_t stream) {
  (void)in_sizes; (void)n_in; (void)out_size; (void)ws_size;
  const float* pts = (const float*)d_in[0];
  float* out = (float*)d_out;
  ull* ws = (ull*)d_ws;
  fps_kernel<<<dim3(NB * WPB), dim3(TPB), 0, stream>>>(pts, out, ws);
}